// Round 2
// baseline (1255.874 us; speedup 1.0000x reference)
//
#include <hip/hip_runtime.h>

#define N_ 100000
#define E_ 1600000
#define HD 128

// ---------------------------------------------------------------------------
// Accumulating matmul chunk: 16 nodes (this thread's half) x K -> feature f.
// Activations in LDS (row stride RS), weights [K,128] from global (L2-hot).
// LDS reads are wave-uniform rows -> broadcast, conflict-free.
// Caller initializes acc (bias); this accumulates.
// ---------------------------------------------------------------------------
template<int K, int RS>
__device__ __forceinline__ void mmK(const float* __restrict__ hin,
                                    const float* __restrict__ W,
                                    int f, int hh, float acc[16])
{
    for (int k0 = 0; k0 < K; k0 += 16) {
        float w[16];
#pragma unroll
        for (int j = 0; j < 16; ++j) w[j] = W[(k0 + j) * HD + f];
#pragma unroll
        for (int nn = 0; nn < 16; ++nn) {
            const float4* h4 = (const float4*)(hin + (hh * 16 + nn) * RS + k0);
            float4 h0 = h4[0], h1 = h4[1], h2 = h4[2], h3 = h4[3];
            acc[nn] += h0.x * w[0] + h0.y * w[1] + h0.z * w[2] + h0.w * w[3]
                     + h1.x * w[4] + h1.y * w[5] + h1.z * w[6] + h1.w * w[7]
                     + h2.x * w[8] + h2.y * w[9] + h2.z * w[10] + h2.w * w[11]
                     + h3.x * w[12] + h3.y * w[13] + h3.z * w[14] + h3.w * w[15];
        }
    }
}

// layer 1 (16 -> 128) helper: xs[32][16] -> dst[32][128], ReLU
__device__ __forceinline__ void layer1(const float xs[32][16],
                                       const float* __restrict__ W1,
                                       const float* __restrict__ b1,
                                       float dst[32][HD], int f, int hh)
{
    float w[16];
#pragma unroll
    for (int j = 0; j < 16; ++j) w[j] = W1[j * HD + f];
    const float bb = b1[f];
#pragma unroll
    for (int nn = 0; nn < 16; ++nn) {
        const int n = hh * 16 + nn;
        const float4* h4 = (const float4*)xs[n];
        float4 h0 = h4[0], h1 = h4[1], h2 = h4[2], h3 = h4[3];
        float a = bb
            + h0.x * w[0] + h0.y * w[1] + h0.z * w[2] + h0.w * w[3]
            + h1.x * w[4] + h1.y * w[5] + h1.z * w[6] + h1.w * w[7]
            + h2.x * w[8] + h2.y * w[9] + h2.z * w[10] + h2.w * w[11]
            + h3.x * w[12] + h3.y * w[13] + h3.z * w[14] + h3.w * w[15];
        dst[n][f] = fmaxf(a, 0.f);
    }
}

// ---------------------------------------------------------------------------
// K1: mlp_pre chain + lin, writes ONLY msg[N,128].
// ---------------------------------------------------------------------------
__global__ __launch_bounds__(256) void k_msg(
    const float* __restrict__ x,
    const float* __restrict__ W1, const float* __restrict__ b1,
    const float* __restrict__ W2, const float* __restrict__ b2,
    const float* __restrict__ W3, const float* __restrict__ b3,
    const float* __restrict__ Wl, const float* __restrict__ bl,
    float* __restrict__ msg)
{
    __shared__ float xs[32][16];
    __shared__ float hA[32][HD];
    __shared__ float hB[32][HD];
    const int tid = threadIdx.x;
    const int f   = tid & 127;
    const int hh  = tid >> 7;
    const int base = blockIdx.x * 32;

    for (int i = tid; i < 32 * 16; i += 256)
        xs[i >> 4][i & 15] = x[(base + (i >> 4)) * 16 + (i & 15)];
    __syncthreads();

    float acc[16];

    layer1(xs, W1, b1, hA, f, hh);
    __syncthreads();

#pragma unroll
    for (int nn = 0; nn < 16; ++nn) acc[nn] = b2[f];
    mmK<HD, HD>(&hA[0][0], W2, f, hh, acc);
#pragma unroll
    for (int nn = 0; nn < 16; ++nn) hB[hh * 16 + nn][f] = fmaxf(acc[nn], 0.f);
    __syncthreads();

#pragma unroll
    for (int nn = 0; nn < 16; ++nn) acc[nn] = b3[f];
    mmK<HD, HD>(&hB[0][0], W3, f, hh, acc);
#pragma unroll
    for (int nn = 0; nn < 16; ++nn) hA[hh * 16 + nn][f] = fmaxf(acc[nn], 0.f);
    __syncthreads();

#pragma unroll
    for (int nn = 0; nn < 16; ++nn) acc[nn] = bl[f];
    mmK<HD, HD>(&hA[0][0], Wl, f, hh, acc);
#pragma unroll
    for (int nn = 0; nn < 16; ++nn)
        msg[(size_t)(base + hh * 16 + nn) * HD + f] = fmaxf(acc[nn], 0.f);
}

// ---------------------------------------------------------------------------
// CSR build: histogram -> scan -> fill
// ---------------------------------------------------------------------------
__global__ void k_hist(const int* __restrict__ dst, int* __restrict__ deg)
{
    int e = blockIdx.x * 256 + threadIdx.x;
    if (e < E_) atomicAdd(&deg[dst[e]], 1);
}

__global__ void k_bsum(const int* __restrict__ deg, int* __restrict__ part)
{
    __shared__ int s[256];
    int i = blockIdx.x * 256 + threadIdx.x;
    int t = threadIdx.x;
    s[t] = (i < N_) ? deg[i] : 0;
    __syncthreads();
    for (int st = 128; st > 0; st >>= 1) {
        if (t < st) s[t] += s[t + st];
        __syncthreads();
    }
    if (t == 0) part[blockIdx.x] = s[0];
}

__global__ void k_pscan(const int* __restrict__ part, int* __restrict__ poff, int nb)
{
    __shared__ int s[512];
    int t = threadIdx.x;
    int d = (t < nb) ? part[t] : 0;
    s[t] = d;
    __syncthreads();
    for (int st = 1; st < 512; st <<= 1) {
        int v = (t >= st) ? s[t - st] : 0;
        __syncthreads();
        s[t] += v;
        __syncthreads();
    }
    if (t < nb) poff[t] = s[t] - d;
}

__global__ void k_scan(const int* __restrict__ deg, const int* __restrict__ poff,
                       int* __restrict__ offs, int* __restrict__ cursor)
{
    __shared__ int s[256];
    int i = blockIdx.x * 256 + threadIdx.x;
    int t = threadIdx.x;
    int d = (i < N_) ? deg[i] : 0;
    s[t] = d;
    __syncthreads();
    for (int st = 1; st < 256; st <<= 1) {
        int v = (t >= st) ? s[t - st] : 0;
        __syncthreads();
        s[t] += v;
        __syncthreads();
    }
    if (i < N_) {
        int ex = s[t] - d + poff[blockIdx.x];
        offs[i] = ex;
        cursor[i] = ex;
    }
}

__global__ void k_fill(const int* __restrict__ src, const int* __restrict__ dst,
                       int* __restrict__ cursor, int* __restrict__ csr)
{
    int e = blockIdx.x * 256 + threadIdx.x;
    if (e < E_) {
        int pos = atomicAdd(&cursor[dst[e]], 1);
        csr[pos] = src[e];
    }
}

// ---------------------------------------------------------------------------
// K3: recompute pre (16->128->128->128) + fused CSR gather + mlp_post.
// LDS: xs 2K + hA/hB/hG 16K each = 50 KB.
// ---------------------------------------------------------------------------
__global__ __launch_bounds__(256) void k_post(
    const float* __restrict__ x,
    const float* __restrict__ msg, const int* __restrict__ csr,
    const int* __restrict__ offs, const int* __restrict__ endp,
    const float* __restrict__ W1, const float* __restrict__ b1,
    const float* __restrict__ W2, const float* __restrict__ b2,
    const float* __restrict__ W3, const float* __restrict__ b3,
    const float* __restrict__ P1, const float* __restrict__ pb1,
    const float* __restrict__ P2, const float* __restrict__ pb2,
    const float* __restrict__ P3, const float* __restrict__ pb3,
    float* __restrict__ out)
{
    __shared__ float xs[32][16];
    __shared__ float hA[32][HD];   // pre
    __shared__ float hB[32][HD];   // ping
    __shared__ float hG[32][HD];   // agg, then h2
    const int tid = threadIdx.x;
    const int f   = tid & 127;
    const int hh  = tid >> 7;
    const int base = blockIdx.x * 32;

    for (int i = tid; i < 32 * 16; i += 256)
        xs[i >> 4][i & 15] = x[(base + (i >> 4)) * 16 + (i & 15)];
    __syncthreads();

    float acc[16];

    // ---- recompute pre: L1 -> hB, L2 -> hA, L3 -> hA(final via hB) ----
    layer1(xs, W1, b1, hB, f, hh);
    __syncthreads();

#pragma unroll
    for (int nn = 0; nn < 16; ++nn) acc[nn] = b2[f];
    mmK<HD, HD>(&hB[0][0], W2, f, hh, acc);
#pragma unroll
    for (int nn = 0; nn < 16; ++nn) hG[hh * 16 + nn][f] = fmaxf(acc[nn], 0.f);
    __syncthreads();

#pragma unroll
    for (int nn = 0; nn < 16; ++nn) acc[nn] = b3[f];
    mmK<HD, HD>(&hG[0][0], W3, f, hh, acc);
#pragma unroll
    for (int nn = 0; nn < 16; ++nn) hA[hh * 16 + nn][f] = fmaxf(acc[nn], 0.f);
    __syncthreads();   // hA = pre; hB, hG free

    // ---- fused gather: wave w owns nodes w*8 .. w*8+7 ----
    {
        const int w = tid >> 6, l = tid & 63;
        for (int j = 0; j < 8; ++j) {
            const int n = w * 8 + j;
            const int node = base + n;
            const int s = offs[node], e = endp[node];
            float a0 = 0.f, a1 = 0.f;
            for (int i = s; i < e; ++i) {
                const float* row = msg + (size_t)csr[i] * HD;
                a0 += row[l];
                a1 += row[l + 64];
            }
            hG[n][l] = a0;
            hG[n][l + 64] = a1;
        }
    }
    __syncthreads();   // hG = agg

    // ---- P1: [pre | agg] @ P1 (split into two 128-K accumulations) ----
#pragma unroll
    for (int nn = 0; nn < 16; ++nn) acc[nn] = pb1[f];
    mmK<HD, HD>(&hA[0][0], P1, f, hh, acc);              // pre part (rows 0..127)
    mmK<HD, HD>(&hG[0][0], P1 + HD * HD, f, hh, acc);    // agg part (rows 128..255)
#pragma unroll
    for (int nn = 0; nn < 16; ++nn) hB[hh * 16 + nn][f] = fmaxf(acc[nn], 0.f);
    __syncthreads();

    // ---- P2 ----
#pragma unroll
    for (int nn = 0; nn < 16; ++nn) acc[nn] = pb2[f];
    mmK<HD, HD>(&hB[0][0], P2, f, hh, acc);
#pragma unroll
    for (int nn = 0; nn < 16; ++nn) hG[hh * 16 + nn][f] = fmaxf(acc[nn], 0.f);
    __syncthreads();   // hG = h2

    // ---- P3: 128 -> 16 + outer ReLU ----
    {
        const int o = tid & 15;
        const int q = tid >> 4;
#pragma unroll
        for (int p = 0; p < 2; ++p) {
            const int n = p * 16 + q;
            float a = pb3[o];
            for (int k = 0; k < HD; k += 4) {
                const float4 h = *(const float4*)&hG[n][k];
                a += h.x * P3[(k + 0) * 16 + o] + h.y * P3[(k + 1) * 16 + o]
                   + h.z * P3[(k + 2) * 16 + o] + h.w * P3[(k + 3) * 16 + o];
            }
            out[(size_t)(base + n) * 16 + o] = fmaxf(a, 0.f);
        }
    }
}

// ---------------------------------------------------------------------------
extern "C" void kernel_launch(void* const* d_in, const int* in_sizes, int n_in,
                              void* d_out, int out_size, void* d_ws, size_t ws_size,
                              hipStream_t stream)
{
    const float* x  = (const float*)d_in[0];
    const int*   ei = (const int*)d_in[1];
    const float* W1 = (const float*)d_in[2];  const float* b1  = (const float*)d_in[3];
    const float* W2 = (const float*)d_in[4];  const float* b2  = (const float*)d_in[5];
    const float* W3 = (const float*)d_in[6];  const float* b3  = (const float*)d_in[7];
    const float* Wl = (const float*)d_in[8];  const float* bl  = (const float*)d_in[9];
    const float* P1 = (const float*)d_in[10]; const float* pb1 = (const float*)d_in[11];
    const float* P2 = (const float*)d_in[12]; const float* pb2 = (const float*)d_in[13];
    const float* P3 = (const float*)d_in[14]; const float* pb3 = (const float*)d_in[15];
    float* out = (float*)d_out;

    // Workspace: 51.2 + 6.4 + 3*0.4 + ~0 MB  =  ~58.9 MB total.
    char* ws = (char*)d_ws;
    float* msg  = (float*)ws; ws += (size_t)N_ * HD * 4;
    int* csr    = (int*)ws;   ws += (size_t)E_ * 4;
    int* deg    = (int*)ws;   ws += (size_t)N_ * 4;
    int* offs   = (int*)ws;   ws += (size_t)N_ * 4;
    int* cursor = (int*)ws;   ws += (size_t)N_ * 4;
    int* part   = (int*)ws;   ws += 512 * 4;
    int* poff   = (int*)ws;   ws += 512 * 4;

    const int* srcv = ei;
    const int* dstv = ei + E_;

    const int nbN = (N_ + 255) / 256;   // 391
    const int nbE = (E_ + 255) / 256;

    hipMemsetAsync(deg, 0, (size_t)N_ * 4, stream);
    k_msg<<<N_ / 32, 256, 0, stream>>>(x, W1, b1, W2, b2, W3, b3, Wl, bl, msg);
    k_hist<<<nbE, 256, 0, stream>>>(dstv, deg);
    k_bsum<<<nbN, 256, 0, stream>>>(deg, part);
    k_pscan<<<1, 512, 0, stream>>>(part, poff, nbN);
    k_scan<<<nbN, 256, 0, stream>>>(deg, poff, offs, cursor);
    k_fill<<<nbE, 256, 0, stream>>>(srcv, dstv, cursor, csr);
    k_post<<<N_ / 32, 256, 0, stream>>>(x, msg, csr, offs, cursor,
                                        W1, b1, W2, b2, W3, b3,
                                        P1, pb1, P2, pb2, P3, pb3, out);
}

// Round 3
// 440.028 us; speedup vs baseline: 2.8541x; 2.8541x over previous
//
#include <hip/hip_runtime.h>

#define N_ 100000
#define E_ 1600000
#define HD 128

typedef unsigned short u16;
typedef unsigned int u32;
typedef __bf16 bf16x8 __attribute__((ext_vector_type(8)));
typedef float f32x4 __attribute__((ext_vector_type(4)));

// packed-weight element counts / offsets (in u16 elements)
#define OFF_W2 0
#define OFF_W3 16384
#define OFF_WL 32768
#define OFF_P2 49152
#define OFF_P1 65536
#define PK_TOT 98304   // hi plane size; lo plane at +PK_TOT

__device__ __forceinline__ u16 f2bf(float f) {
    u32 u = __float_as_uint(f);
    return (u16)((u + 0x7FFFu + ((u >> 16) & 1u)) >> 16);
}
__device__ __forceinline__ float bf2f(u16 h) {
    return __uint_as_float(((u32)h) << 16);
}
__device__ __forceinline__ f32x4 mfma16(uint4 a, uint4 b, f32x4 c) {
    return __builtin_amdgcn_mfma_f32_16x16x32_bf16(
        __builtin_bit_cast(bf16x8, a), __builtin_bit_cast(bf16x8, b), c, 0, 0, 0);
}

// Activation LDS layout (u16 array, [rows][128]): idx = row*128 + (col ^ ((row&7)<<3))
// A-fragment (mfma_f32_16x16x32_bf16): lane l holds A[row=l&15][k=8*(l>>4)+j], j=0..7
__device__ __forceinline__ uint4 ldsA(const u16* A, int row, int kt, int l) {
    int idx = row * 128 + (((kt * 32 + ((l >> 4) << 3))) ^ ((row & 7) << 3));
    return *(const uint4*)&A[idx];
}

// write C fragment (col=l&15 (+16*nt), row=4*(l>>4)+r (+16*mt)) as ReLU'd hi/lo bf16
__device__ __forceinline__ void writeAct(u16* Ah, u16* Al, f32x4 acc, int mt, int nt, int l) {
    const int col = nt * 16 + (l & 15);
#pragma unroll
    for (int r = 0; r < 4; ++r) {
        const int row = mt * 16 + ((l >> 4) << 2) + r;
        float a = fmaxf(acc[r], 0.f);
        u16 h = f2bf(a);
        const int idx = row * 128 + (col ^ ((row & 7) << 3));
        Ah[idx] = h;
        Al[idx] = f2bf(a - bf2f(h));
    }
}

// One MFMA layer: C[MT*16 x 128] = relu-pending( A[MT*16 x KT*32] @ W + bias )
// Wave w owns n-tiles 2w, 2w+1. hi/lo split: C += Ah*Bh + Ah*Bl + Al*Bh.
template<int MT, int KT>
__device__ __forceinline__ void mfmaLayer(const u16* Ah, const u16* Al,
                                          const u16* __restrict__ wph,
                                          const u16* __restrict__ wpl,
                                          const float* __restrict__ bias,
                                          int w, int l, f32x4 acc[MT][2])
{
    const int col0 = 2 * w * 16 + (l & 15);
#pragma unroll
    for (int mt = 0; mt < MT; ++mt)
#pragma unroll
        for (int nti = 0; nti < 2; ++nti) {
            float bv = bias[col0 + nti * 16];
            acc[mt][nti][0] = bv; acc[mt][nti][1] = bv;
            acc[mt][nti][2] = bv; acc[mt][nti][3] = bv;
        }
#pragma unroll
    for (int kt = 0; kt < KT; ++kt) {
        uint4 ah[MT], al[MT];
#pragma unroll
        for (int mt = 0; mt < MT; ++mt) {
            ah[mt] = ldsA(Ah, mt * 16 + (l & 15), kt, l);
            al[mt] = ldsA(Al, mt * 16 + (l & 15), kt, l);
        }
#pragma unroll
        for (int nti = 0; nti < 2; ++nti) {
            const int nt = 2 * w + nti;
            uint4 bh = *(const uint4*)&wph[((nt * KT + kt) * 64 + l) * 8];
            uint4 bl = *(const uint4*)&wpl[((nt * KT + kt) * 64 + l) * 8];
#pragma unroll
            for (int mt = 0; mt < MT; ++mt) {
                acc[mt][nti] = mfma16(ah[mt], bh, acc[mt][nti]);
                acc[mt][nti] = mfma16(ah[mt], bl, acc[mt][nti]);
                acc[mt][nti] = mfma16(al[mt], bh, acc[mt][nti]);
            }
        }
    }
}

// ---------------------------------------------------------------------------
// Weight pre-pack: fragment-ordered bf16 hi/lo planes.
// Element e of matrix (offset OFF): e = OFF + ((nt*KT+kt)*64 + lane)*8 + j,
// holds W[kt*32 + 8*(lane>>4) + j][nt*16 + (lane&15)].
// ---------------------------------------------------------------------------
__global__ __launch_bounds__(256) void k_pack(
    const float* __restrict__ W2, const float* __restrict__ W3,
    const float* __restrict__ Wl, const float* __restrict__ P2,
    const float* __restrict__ P1, u16* __restrict__ wpk)
{
    int e = blockIdx.x * 256 + threadIdx.x;
    if (e >= PK_TOT) return;
    const float* src; int local, KT;
    if (e < OFF_P1) {
        int m = e >> 14;
        src = (m == 0) ? W2 : (m == 1) ? W3 : (m == 2) ? Wl : P2;
        local = e & 16383; KT = 4;
    } else {
        src = P1; local = e - OFF_P1; KT = 8;
    }
    int j = local & 7, lane = (local >> 3) & 63, t = local >> 9;
    int kt = t % KT, nt = t / KT;
    int k = kt * 32 + ((lane >> 4) << 3) + j;
    int n = nt * 16 + (lane & 15);
    float v = src[k * HD + n];
    u16 h = f2bf(v);
    wpk[e] = h;
    wpk[PK_TOT + e] = f2bf(v - bf2f(h));
}

// ---------------------------------------------------------------------------
// layer1 (16 -> 128) VALU fp32, output as hi/lo bf16 into U. NPH nodes/thread.
// ---------------------------------------------------------------------------
template<int NPH>
__device__ __forceinline__ void layer1(const float xs[][16],
                                       const float* __restrict__ W1,
                                       const float* __restrict__ b1,
                                       u16* Uh, u16* Ul, int f, int g)
{
    float w[16];
#pragma unroll
    for (int j = 0; j < 16; ++j) w[j] = W1[j * HD + f];
    const float bb = b1[f];
#pragma unroll
    for (int nn = 0; nn < NPH; ++nn) {
        const int row = g * NPH + nn;
        const float4* h4 = (const float4*)xs[row];
        float4 h0 = h4[0], h1 = h4[1], h2 = h4[2], h3 = h4[3];
        float a = bb
            + h0.x * w[0] + h0.y * w[1] + h0.z * w[2] + h0.w * w[3]
            + h1.x * w[4] + h1.y * w[5] + h1.z * w[6] + h1.w * w[7]
            + h2.x * w[8] + h2.y * w[9] + h2.z * w[10] + h2.w * w[11]
            + h3.x * w[12] + h3.y * w[13] + h3.z * w[14] + h3.w * w[15];
        a = fmaxf(a, 0.f);
        u16 h = f2bf(a);
        const int idx = row * 128 + (f ^ ((row & 7) << 3));
        Uh[idx] = h;
        Ul[idx] = f2bf(a - bf2f(h));
    }
}

// ---------------------------------------------------------------------------
// K1: mlp_pre + lin -> msg[N,128].  32 nodes / 256-thread block.
// ---------------------------------------------------------------------------
__global__ __launch_bounds__(256) void k_msg(
    const float* __restrict__ x,
    const float* __restrict__ W1, const float* __restrict__ b1,
    const float* __restrict__ b2, const float* __restrict__ b3,
    const float* __restrict__ bl,
    const u16* __restrict__ wpk, float* __restrict__ msg)
{
    __shared__ float xs[32][16];
    __shared__ __align__(16) u16 Uh[4096], Ul[4096], Vh[4096], Vl[4096];
    const int tid = threadIdx.x;
    const int l = tid & 63, w = tid >> 6;
    const int base = blockIdx.x * 32;

    for (int i = tid; i < 32 * 16; i += 256)
        xs[i >> 4][i & 15] = x[(base + (i >> 4)) * 16 + (i & 15)];
    __syncthreads();

    layer1<16>(xs, W1, b1, Uh, Ul, tid & 127, tid >> 7);
    __syncthreads();

    f32x4 acc[2][2];
    // W2: U -> V
    mfmaLayer<2, 4>(Uh, Ul, wpk + OFF_W2, wpk + PK_TOT + OFF_W2, b2, w, l, acc);
#pragma unroll
    for (int mt = 0; mt < 2; ++mt)
#pragma unroll
        for (int nti = 0; nti < 2; ++nti) writeAct(Vh, Vl, acc[mt][nti], mt, 2 * w + nti, l);
    __syncthreads();

    // W3: V -> U
    mfmaLayer<2, 4>(Vh, Vl, wpk + OFF_W3, wpk + PK_TOT + OFF_W3, b3, w, l, acc);
#pragma unroll
    for (int mt = 0; mt < 2; ++mt)
#pragma unroll
        for (int nti = 0; nti < 2; ++nti) writeAct(Uh, Ul, acc[mt][nti], mt, 2 * w + nti, l);
    __syncthreads();

    // lin: U -> msg (fp32 stores)
    mfmaLayer<2, 4>(Uh, Ul, wpk + OFF_WL, wpk + PK_TOT + OFF_WL, bl, w, l, acc);
#pragma unroll
    for (int mt = 0; mt < 2; ++mt)
#pragma unroll
        for (int nti = 0; nti < 2; ++nti) {
            const int col = (2 * w + nti) * 16 + (l & 15);
#pragma unroll
            for (int r = 0; r < 4; ++r) {
                const int row = mt * 16 + ((l >> 4) << 2) + r;
                msg[(size_t)(base + row) * HD + col] = fmaxf(acc[mt][nti][r], 0.f);
            }
        }
}

// ---------------------------------------------------------------------------
// CSR build (unchanged from round 2)
// ---------------------------------------------------------------------------
__global__ void k_hist(const int* __restrict__ dst, int* __restrict__ deg)
{
    int e = blockIdx.x * 256 + threadIdx.x;
    if (e < E_) atomicAdd(&deg[dst[e]], 1);
}

__global__ void k_bsum(const int* __restrict__ deg, int* __restrict__ part)
{
    __shared__ int s[256];
    int i = blockIdx.x * 256 + threadIdx.x;
    int t = threadIdx.x;
    s[t] = (i < N_) ? deg[i] : 0;
    __syncthreads();
    for (int st = 128; st > 0; st >>= 1) {
        if (t < st) s[t] += s[t + st];
        __syncthreads();
    }
    if (t == 0) part[blockIdx.x] = s[0];
}

__global__ void k_pscan(const int* __restrict__ part, int* __restrict__ poff, int nb)
{
    __shared__ int s[512];
    int t = threadIdx.x;
    int d = (t < nb) ? part[t] : 0;
    s[t] = d;
    __syncthreads();
    for (int st = 1; st < 512; st <<= 1) {
        int v = (t >= st) ? s[t - st] : 0;
        __syncthreads();
        s[t] += v;
        __syncthreads();
    }
    if (t < nb) poff[t] = s[t] - d;
}

__global__ void k_scan(const int* __restrict__ deg, const int* __restrict__ poff,
                       int* __restrict__ offs, int* __restrict__ cursor)
{
    __shared__ int s[256];
    int i = blockIdx.x * 256 + threadIdx.x;
    int t = threadIdx.x;
    int d = (i < N_) ? deg[i] : 0;
    s[t] = d;
    __syncthreads();
    for (int st = 1; st < 256; st <<= 1) {
        int v = (t >= st) ? s[t - st] : 0;
        __syncthreads();
        s[t] += v;
        __syncthreads();
    }
    if (i < N_) {
        int ex = s[t] - d + poff[blockIdx.x];
        offs[i] = ex;
        cursor[i] = ex;
    }
}

__global__ void k_fill(const int* __restrict__ src, const int* __restrict__ dst,
                       int* __restrict__ cursor, int* __restrict__ csr)
{
    int e = blockIdx.x * 256 + threadIdx.x;
    if (e < E_) {
        int pos = atomicAdd(&cursor[dst[e]], 1);
        csr[pos] = src[e];
    }
}

// ---------------------------------------------------------------------------
// K3: recompute pre (MFMA) + fused CSR gather + mlp_post (MFMA) -> out.
// 16 nodes / 256-thread block; LDS 25.6 KB -> 6 blocks/CU.
// ---------------------------------------------------------------------------
__global__ __launch_bounds__(256) void k_post(
    const float* __restrict__ x,
    const float* __restrict__ msg, const int* __restrict__ csr,
    const int* __restrict__ offs, const int* __restrict__ endp,
    const float* __restrict__ W1, const float* __restrict__ b1,
    const float* __restrict__ b2, const float* __restrict__ b3,
    const float* __restrict__ pb1, const float* __restrict__ pb2,
    const float* __restrict__ P3, const float* __restrict__ pb3,
    const u16* __restrict__ wpk, float* __restrict__ out)
{
    __shared__ float xs[16][16];
    __shared__ __align__(16) u16 Uh[2048], Ul[2048], Vh[2048], Vl[2048];
    __shared__ float hG[16][128];
    const int tid = threadIdx.x;
    const int l = tid & 63, w = tid >> 6;
    const int base = blockIdx.x * 16;

    if (tid < 256) xs[tid >> 4][tid & 15] = x[(base + (tid >> 4)) * 16 + (tid & 15)];
    __syncthreads();

    layer1<8>(xs, W1, b1, Uh, Ul, tid & 127, tid >> 7);
    __syncthreads();

    f32x4 acc[1][2];
    // W2: U -> V (h2)
    mfmaLayer<1, 4>(Uh, Ul, wpk + OFF_W2, wpk + PK_TOT + OFF_W2, b2, w, l, acc);
#pragma unroll
    for (int nti = 0; nti < 2; ++nti) writeAct(Vh, Vl, acc[0][nti], 0, 2 * w + nti, l);
    __syncthreads();

    // W3: V -> U (pre)
    mfmaLayer<1, 4>(Vh, Vl, wpk + OFF_W3, wpk + PK_TOT + OFF_W3, b3, w, l, acc);
#pragma unroll
    for (int nti = 0; nti < 2; ++nti) writeAct(Uh, Ul, acc[0][nti], 0, 2 * w + nti, l);
    __syncthreads();

    // gather: wave w -> nodes w*4 .. w*4+3, ILP-4 unrolled
    for (int j = 0; j < 4; ++j) {
        const int n = w * 4 + j;
        const int node = base + n;
        const int s = offs[node], e = endp[node];
        float a0 = 0.f, a1 = 0.f;
        int i = s;
        for (; i + 4 <= e; i += 4) {
            int c0 = csr[i], c1 = csr[i + 1], c2 = csr[i + 2], c3 = csr[i + 3];
            const float* r0 = msg + (size_t)c0 * HD;
            const float* r1 = msg + (size_t)c1 * HD;
            const float* r2 = msg + (size_t)c2 * HD;
            const float* r3 = msg + (size_t)c3 * HD;
            a0 += (r0[l] + r1[l]) + (r2[l] + r3[l]);
            a1 += (r0[l + 64] + r1[l + 64]) + (r2[l + 64] + r3[l + 64]);
        }
        for (; i < e; ++i) {
            const float* r = msg + (size_t)csr[i] * HD;
            a0 += r[l];
            a1 += r[l + 64];
        }
        hG[n][l] = a0;
        hG[n][l + 64] = a1;
    }
    __syncthreads();

    // convert agg (hG fp32) -> V (hi/lo frag layout)
    {
        const int i0 = tid * 8;
        const int row = i0 >> 7, c0 = i0 & 127;
        const int idx = row * 128 + (c0 ^ ((row & 7) << 3));
#pragma unroll
        for (int j = 0; j < 8; ++j) {
            float a = hG[row][c0 + j];
            u16 h = f2bf(a);
            Vh[idx + j] = h;
            Vl[idx + j] = f2bf(a - bf2f(h));
        }
    }
    __syncthreads();

    // P1: K=256 -> kt 0-3 read U (pre), kt 4-7 read V (agg)
    {
        const int col0 = 2 * w * 16 + (l & 15);
#pragma unroll
        for (int nti = 0; nti < 2; ++nti) {
            float bv = pb1[col0 + nti * 16];
            acc[0][nti][0] = bv; acc[0][nti][1] = bv;
            acc[0][nti][2] = bv; acc[0][nti][3] = bv;
        }
#pragma unroll
        for (int kt = 0; kt < 8; ++kt) {
            const u16* sh = (kt < 4) ? Uh : Vh;
            const u16* sl = (kt < 4) ? Ul : Vl;
            uint4 ah = ldsA(sh, l & 15, kt & 3, l);
            uint4 al = ldsA(sl, l & 15, kt & 3, l);
#pragma unroll
            for (int nti = 0; nti < 2; ++nti) {
                const int nt = 2 * w + nti;
                uint4 bh = *(const uint4*)&wpk[OFF_P1 + ((nt * 8 + kt) * 64 + l) * 8];
                uint4 bl = *(const uint4*)&wpk[PK_TOT + OFF_P1 + ((nt * 8 + kt) * 64 + l) * 8];
                acc[0][nti] = mfma16(ah, bh, acc[0][nti]);
                acc[0][nti] = mfma16(ah, bl, acc[0][nti]);
                acc[0][nti] = mfma16(al, bh, acc[0][nti]);
            }
        }
    }
    __syncthreads();   // all reads of U done before overwrite
#pragma unroll
    for (int nti = 0; nti < 2; ++nti) writeAct(Uh, Ul, acc[0][nti], 0, 2 * w + nti, l);
    __syncthreads();

    // P2: U -> hG (fp32, post-ReLU)
    mfmaLayer<1, 4>(Uh, Ul, wpk + OFF_P2, wpk + PK_TOT + OFF_P2, pb2, w, l, acc);
#pragma unroll
    for (int nti = 0; nti < 2; ++nti) {
        const int col = (2 * w + nti) * 16 + (l & 15);
#pragma unroll
        for (int r = 0; r < 4; ++r)
            hG[((l >> 4) << 2) + r][col] = fmaxf(acc[0][nti][r], 0.f);
    }
    __syncthreads();

    // P3: 128 -> 16 + outer ReLU (VALU fp32)
    {
        const int o = tid & 15;
        const int n = tid >> 4;
        float a = pb3[o];
        for (int k = 0; k < HD; k += 4) {
            const float4 h = *(const float4*)&hG[n][k];
            a += h.x * P3[(k + 0) * 16 + o] + h.y * P3[(k + 1) * 16 + o]
               + h.z * P3[(k + 2) * 16 + o] + h.w * P3[(k + 3) * 16 + o];
        }
        out[(size_t)(base + n) * 16 + o] = fmaxf(a, 0.f);
    }
}

// ---------------------------------------------------------------------------
extern "C" void kernel_launch(void* const* d_in, const int* in_sizes, int n_in,
                              void* d_out, int out_size, void* d_ws, size_t ws_size,
                              hipStream_t stream)
{
    const float* x  = (const float*)d_in[0];
    const int*   ei = (const int*)d_in[1];
    const float* W1 = (const float*)d_in[2];  const float* b1  = (const float*)d_in[3];
    const float* W2 = (const float*)d_in[4];  const float* b2  = (const float*)d_in[5];
    const float* W3 = (const float*)d_in[6];  const float* b3  = (const float*)d_in[7];
    const float* Wl = (const float*)d_in[8];  const float* bl  = (const float*)d_in[9];
    const float* P1 = (const float*)d_in[10]; const float* pb1 = (const float*)d_in[11];
    const float* P2 = (const float*)d_in[12]; const float* pb2 = (const float*)d_in[13];
    const float* P3 = (const float*)d_in[14]; const float* pb3 = (const float*)d_in[15];
    float* out = (float*)d_out;

    // Workspace: msg 51.2 MB + csr 6.4 MB + ints 1.2 MB + packed weights 0.4 MB
    char* ws = (char*)d_ws;
    float* msg  = (float*)ws; ws += (size_t)N_ * HD * 4;
    int* csr    = (int*)ws;   ws += (size_t)E_ * 4;
    int* deg    = (int*)ws;   ws += (size_t)N_ * 4;
    int* offs   = (int*)ws;   ws += (size_t)N_ * 4;
    int* cursor = (int*)ws;   ws += (size_t)N_ * 4;
    int* part   = (int*)ws;   ws += 512 * 4;
    int* poff   = (int*)ws;   ws += 512 * 4;
    u16* wpk    = (u16*)ws;   ws += (size_t)2 * PK_TOT * 2;

    const int* srcv = ei;
    const int* dstv = ei + E_;

    const int nbN = (N_ + 255) / 256;   // 391
    const int nbE = (E_ + 255) / 256;

    hipMemsetAsync(deg, 0, (size_t)N_ * 4, stream);
    k_pack<<<(PK_TOT + 255) / 256, 256, 0, stream>>>(W2, W3, Wl, P2, P1, wpk);
    k_msg<<<N_ / 32, 256, 0, stream>>>(x, W1, b1, b2, b3, bl, wpk, msg);
    k_hist<<<nbE, 256, 0, stream>>>(dstv, deg);
    k_bsum<<<nbN, 256, 0, stream>>>(deg, part);
    k_pscan<<<1, 512, 0, stream>>>(part, poff, nbN);
    k_scan<<<nbN, 256, 0, stream>>>(deg, poff, offs, cursor);
    k_fill<<<nbE, 256, 0, stream>>>(srcv, dstv, cursor, csr);
    k_post<<<N_ / 16, 256, 0, stream>>>(x, msg, csr, offs, cursor,
                                        W1, b1, b2, b3, pb1, pb2, P3, pb3,
                                        wpk, out);
}